// Round 4
// baseline (692.829 us; speedup 1.0000x reference)
//
#include <hip/hip_runtime.h>
#include <math.h>

namespace {
constexpr int kB = 4, kN = 6, kC = 64, kD = 41, kFH = 16, kFW = 44;
constexpr int kNX0 = 200, kNX1 = 200;
constexpr int kPix = kB * kN * kFH * kFW;          // 16896 pixels
constexpr int kPts = kPix * kD;                    // 692736 points
constexpr int kVox = kB * kNX0 * kNX1;             // 160000 voxels
constexpr int kPvElems = kPix * kC;                // 1081344
constexpr int kScanBlks = kVox / 256;              // 625 (exact)

// ws carve
constexpr size_t kOffPvT    = 0;
constexpr size_t kSzPvT     = (size_t)kPvElems * 4;
constexpr size_t kOffVox    = kOffPvT + kSzPvT;
constexpr size_t kSzVox     = (size_t)kPts * 4;
constexpr size_t kOffWgt    = kOffVox + kSzVox;
constexpr size_t kSzWgt     = (size_t)kPts * 4;
constexpr size_t kOffCnt    = kOffWgt + kSzWgt;
constexpr size_t kSzCnt     = (size_t)kVox * 4;
constexpr size_t kOffOffs   = kOffCnt + kSzCnt;
constexpr size_t kSzOffs    = 640256;              // 160001 u32, padded
constexpr size_t kOffBSum   = kOffOffs + kSzOffs;
constexpr size_t kSzBSum    = 2560;                // 625 u32, padded
constexpr size_t kOffSKey   = kOffBSum + kSzBSum;
constexpr size_t kSzSKey    = (size_t)kPts * 4;
constexpr size_t kOffSWgt   = kOffSKey + kSzSKey;
constexpr size_t kSzSWgt    = (size_t)kPts * 4;
constexpr size_t kWsNeed    = kOffSWgt + kSzSWgt + 256;
}

__device__ __forceinline__ void inv3x3(const float m[9], float inv[9]) {
    float a = m[0], b = m[1], c = m[2];
    float d = m[3], e = m[4], f = m[5];
    float g = m[6], h = m[7], i = m[8];
    float A =  (e * i - f * h);
    float Bm = -(d * i - f * g);
    float Cm =  (d * h - e * g);
    float det = a * A + b * Bm + c * Cm;
    float r = 1.0f / det;
    inv[0] = A * r;
    inv[1] = -(b * i - c * h) * r;
    inv[2] =  (b * f - c * e) * r;
    inv[3] = Bm * r;
    inv[4] =  (a * i - c * g) * r;
    inv[5] = -(a * f - c * d) * r;
    inv[6] = Cm * r;
    inv[7] = -(a * h - b * g) * r;
    inv[8] =  (a * e - b * d) * r;
}

// ---- K0: transpose feat_pv [bn,C,hw] -> pvT [pix][C]; also zero counts ----
__global__ __launch_bounds__(256) void lss_pvt(const float* __restrict__ pv,
                                               float* __restrict__ pvT,
                                               unsigned* __restrict__ counts) {
    int i = blockIdx.x * 256 + threadIdx.x;
    if (i < kPvElems) {
        int c = i & 63;
        int pix = i >> 6;
        int bn = pix / (kFH * kFW), hw = pix % (kFH * kFW);
        pvT[i] = pv[(bn * kC + c) * (kFH * kFW) + hw];
    }
    if (i < kVox) counts[i] = 0u;
}

// ---- K1: per-pixel softmax + geometry -> (vox, wgt) per point + histogram ----
__global__ __launch_bounds__(256) void lss_geom(
    const float* __restrict__ feat_depth,
    const float* __restrict__ rots,
    const float* __restrict__ trans,
    const float* __restrict__ intrins,
    const float* __restrict__ post_rots,
    const float* __restrict__ post_trans,
    int* __restrict__ voxArr, float* __restrict__ wgtArr,
    unsigned* __restrict__ counts)
{
    const int lane = threadIdx.x & 63;
    const int wave = threadIdx.x >> 6;
    const int pix  = blockIdx.x * 4 + wave;

    const int w  = pix % kFW;
    const int h  = (pix / kFW) % kFH;
    const int bn = pix / (kFW * kFH);
    const int b  = bn / kN;

    const float* R  = rots       + bn * 9;
    const float* K  = intrins    + bn * 9;
    const float* PR = post_rots  + bn * 9;
    const float* PT = post_trans + bn * 3;
    const float* T  = trans      + bn * 3;

    float Km[9], PRm[9];
#pragma unroll
    for (int i = 0; i < 9; ++i) { Km[i] = K[i]; PRm[i] = PR[i]; }
    float invK[9], invPR[9];
    inv3x3(Km, invK);
    inv3x3(PRm, invPR);
    float M[9];
#pragma unroll
    for (int i = 0; i < 3; ++i)
#pragma unroll
        for (int j = 0; j < 3; ++j)
            M[i * 3 + j] = R[i * 3 + 0] * invK[0 * 3 + j]
                         + R[i * 3 + 1] * invK[1 * 3 + j]
                         + R[i * 3 + 2] * invK[2 * 3 + j];
    const float pt0 = PT[0], pt1 = PT[1], pt2 = PT[2];
    const float t0 = T[0], t1 = T[1], t2 = T[2];

    const int pixBase = h * kFW + w;
    float fd = -INFINITY;
    if (lane < kD)
        fd = feat_depth[(bn * kD + lane) * (kFH * kFW) + pixBase];
    float mx = fd;
#pragma unroll
    for (int off = 32; off >= 1; off >>= 1)
        mx = fmaxf(mx, __shfl_xor(mx, off));
    float ex = (lane < kD) ? __expf(fd - mx) : 0.0f;
    float sm = ex;
#pragma unroll
    for (int off = 32; off >= 1; off >>= 1)
        sm += __shfl_xor(sm, off);
    const float wgt = ex / sm;

    if (lane < kD) {
        const float u  = (float)w * (703.0f / 43.0f);
        const float v  = (float)h * 17.0f;
        const float dv = 4.0f + (float)lane;
        const float px = u - pt0, py = v - pt1, pz = dv - pt2;
        const float ax = invPR[0] * px + invPR[1] * py + invPR[2] * pz;
        const float ay = invPR[3] * px + invPR[4] * py + invPR[5] * pz;
        const float az = invPR[6] * px + invPR[7] * py + invPR[8] * pz;
        const float qx = ax * az, qy = ay * az, qz = az;
        const float gx = M[0] * qx + M[1] * qy + M[2] * qz + t0;
        const float gy = M[3] * qx + M[4] * qy + M[5] * qz + t1;
        const float gz = M[6] * qx + M[7] * qy + M[8] * qz + t2;
        const float fx = (gx + 50.0f) / 0.5f;
        const float fy = (gy + 50.0f) / 0.5f;
        const float fz = (gz + 10.0f) / 20.0f;
        const int gix = (int)fx;
        const int giy = (int)fy;
        const int giz = (int)fz;
        int flat = -1;
        if (gix >= 0 && gix < kNX0 && giy >= 0 && giy < kNX1 && giz == 0) {
            flat = (b * kNX0 + gix) * kNX1 + giy;
            atomicAdd(&counts[flat], 1u);
        }
        const int p = pix * kD + lane;
        voxArr[p] = flat;
        wgtArr[p] = wgt;
    }
}

// ---- K2a: block-local exclusive scan (625 x 256, exact cover) ----
__global__ __launch_bounds__(256) void lss_scan_a(const unsigned* __restrict__ counts,
                                                  unsigned* __restrict__ offsets,
                                                  unsigned* __restrict__ blockSums) {
    const int i = blockIdx.x * 256 + threadIdx.x;
    const int lane = threadIdx.x & 63;
    const int wv = threadIdx.x >> 6;
    const unsigned c = counts[i];
    unsigned s = c;
#pragma unroll
    for (int o = 1; o < 64; o <<= 1) {
        unsigned v = __shfl_up(s, o);
        if (lane >= o) s += v;
    }
    __shared__ unsigned wsum[4];
    if (lane == 63) wsum[wv] = s;
    __syncthreads();
    unsigned base = 0;
#pragma unroll
    for (int k = 0; k < 3; ++k)
        if (k < wv) base += wsum[k];
    const unsigned incl = s + base;
    offsets[i] = incl - c;
    if (threadIdx.x == 255) blockSums[blockIdx.x] = incl;
}

// ---- K2b: scan 625 block sums (single block) ----
__global__ __launch_bounds__(1024) void lss_scan_b(unsigned* __restrict__ blockSums,
                                                   unsigned* __restrict__ offsets) {
    const int t = threadIdx.x;
    const int lane = t & 63;
    const int wv = t >> 6;
    const unsigned c = (t < kScanBlks) ? blockSums[t] : 0u;
    unsigned s = c;
#pragma unroll
    for (int o = 1; o < 64; o <<= 1) {
        unsigned v = __shfl_up(s, o);
        if (lane >= o) s += v;
    }
    __shared__ unsigned wsum[16];
    if (lane == 63) wsum[wv] = s;
    __syncthreads();
    unsigned base = 0;
#pragma unroll
    for (int k = 0; k < 15; ++k)
        if (k < wv) base += wsum[k];
    const unsigned incl = s + base;
    if (t < kScanBlks) blockSums[t] = incl - c;
    if (t == 1023) offsets[kVox] = incl;
}

// ---- K2c: add block base -> final exclusive offsets ----
__global__ __launch_bounds__(256) void lss_scan_c(const unsigned* __restrict__ blockSums,
                                                  unsigned* __restrict__ offsets) {
    const int i = blockIdx.x * 256 + threadIdx.x;
    offsets[i] += blockSums[blockIdx.x];
}

// ---- K3: scatter points into CSR order; offsets doubles as cursor.
//      After this kernel, offsets[v] == end of segment v (== exclusive start of v+1).
__global__ __launch_bounds__(256) void lss_order(const int* __restrict__ voxArr,
                                                 const float* __restrict__ wgtArr,
                                                 unsigned* __restrict__ offsets,
                                                 unsigned* __restrict__ skey,
                                                 float* __restrict__ swgt) {
    const int p = blockIdx.x * 256 + threadIdx.x;
    if (p < kPts) {
        const int f = voxArr[p];
        if (f >= 0) {
            const unsigned slot = atomicAdd(&offsets[f], 1u);
            const int pix = p / kD;
            const int yi  = f % kNX1;
            const int yl  = yi % 50;
            skey[slot] = (unsigned)pix | ((unsigned)yl << 16);
            swgt[slot] = wgtArr[p];
        }
    }
}

// ---- K4: per-tile balanced gather over the tile's contiguous CSR segment ----
__global__ __launch_bounds__(256) void lss_gather(const float* __restrict__ pvT,
                                                  const unsigned* __restrict__ offsets,
                                                  const unsigned* __restrict__ skey,
                                                  const float* __restrict__ swgt,
                                                  float* __restrict__ out) {
    __shared__ float acc[50][65];
    const int tile = blockIdx.x;
    const int yt = tile & 3;
    const int xi = (tile >> 2) % kNX0;
    const int b  = tile / (kNX0 * 4);
    const int yi0 = yt * 50;
    const int lane = threadIdx.x & 63;
    const int wave = threadIdx.x >> 6;

    for (int e = threadIdx.x; e < 50 * 65; e += 256)
        ((float*)acc)[e] = 0.0f;

    const int flat0 = (b * kNX0 + xi) * kNX1 + yi0;
    const unsigned seg0 = (flat0 == 0) ? 0u : offsets[flat0 - 1];  // mutated: end of prev == start
    const unsigned seg1 = offsets[flat0 + 49];                     // mutated: end of tile
    __syncthreads();

    for (unsigned base = seg0 + 64u * (unsigned)wave; base < seg1; base += 256u) {
        const unsigned idx = min(base + (unsigned)lane, seg1 - 1u);
        const unsigned key = skey[idx];
        const float    w_  = (base + (unsigned)lane < seg1) ? swgt[idx] : 0.0f;
#pragma unroll 16
        for (int k = 0; k < 64; ++k) {
            const unsigned kk = __shfl(key, k);
            const float    wk = __shfl(w_, k);
            const int pk = (int)(kk & 0xFFFFu);
            const int yl = (int)(kk >> 16);
            atomicAdd(&acc[yl][lane], wk * pvT[pk * kC + lane]);
        }
    }
    __syncthreads();

    for (int e = threadIdx.x; e < kC * 50; e += 256) {
        const int c = e / 50, j = e % 50;
        out[((b * kC + c) * (kNX0 * kNX1)) + xi * kNX1 + yi0 + j] = acc[j][c];
    }
}

// ---- fallback: atomic path (used only if ws too small) ----
__global__ __launch_bounds__(256) void lss_scatter_fb(
    const float* __restrict__ feat_depth,
    const float* __restrict__ feat_pv,
    const float* __restrict__ rots,
    const float* __restrict__ trans,
    const float* __restrict__ intrins,
    const float* __restrict__ post_rots,
    const float* __restrict__ post_trans,
    float* __restrict__ out)
{
    const int lane = threadIdx.x & 63;
    const int wave = threadIdx.x >> 6;
    const int pix  = blockIdx.x * 4 + wave;
    const int w  = pix % kFW;
    const int h  = (pix / kFW) % kFH;
    const int bn = pix / (kFW * kFH);
    const int b  = bn / kN;
    const float* R  = rots       + bn * 9;
    const float* K  = intrins    + bn * 9;
    const float* PR = post_rots  + bn * 9;
    const float* PT = post_trans + bn * 3;
    const float* T  = trans      + bn * 3;
    float Km[9], PRm[9];
#pragma unroll
    for (int i = 0; i < 9; ++i) { Km[i] = K[i]; PRm[i] = PR[i]; }
    float invK[9], invPR[9];
    inv3x3(Km, invK);
    inv3x3(PRm, invPR);
    float M[9];
#pragma unroll
    for (int i = 0; i < 3; ++i)
#pragma unroll
        for (int j = 0; j < 3; ++j)
            M[i * 3 + j] = R[i * 3 + 0] * invK[0 * 3 + j]
                         + R[i * 3 + 1] * invK[1 * 3 + j]
                         + R[i * 3 + 2] * invK[2 * 3 + j];
    const float pt0 = PT[0], pt1 = PT[1], pt2 = PT[2];
    const float t0 = T[0], t1 = T[1], t2 = T[2];
    const int pixBase = h * kFW + w;
    float fd = -INFINITY;
    if (lane < kD)
        fd = feat_depth[(bn * kD + lane) * (kFH * kFW) + pixBase];
    float mx = fd;
#pragma unroll
    for (int off = 32; off >= 1; off >>= 1)
        mx = fmaxf(mx, __shfl_xor(mx, off));
    float ex = (lane < kD) ? __expf(fd - mx) : 0.0f;
    float sm = ex;
#pragma unroll
    for (int off = 32; off >= 1; off >>= 1)
        sm += __shfl_xor(sm, off);
    const float wgt = ex / sm;
    int vox = -1;
    if (lane < kD) {
        const float u  = (float)w * (703.0f / 43.0f);
        const float v  = (float)h * 17.0f;
        const float dv = 4.0f + (float)lane;
        const float px = u - pt0, py = v - pt1, pz = dv - pt2;
        const float ax = invPR[0] * px + invPR[1] * py + invPR[2] * pz;
        const float ay = invPR[3] * px + invPR[4] * py + invPR[5] * pz;
        const float az = invPR[6] * px + invPR[7] * py + invPR[8] * pz;
        const float qx = ax * az, qy = ay * az, qz = az;
        const float gx = M[0] * qx + M[1] * qy + M[2] * qz + t0;
        const float gy = M[3] * qx + M[4] * qy + M[5] * qz + t1;
        const float gz = M[6] * qx + M[7] * qy + M[8] * qz + t2;
        const float fx = (gx + 50.0f) / 0.5f;
        const float fy = (gy + 50.0f) / 0.5f;
        const float fz = (gz + 10.0f) / 20.0f;
        const int gix = (int)fx;
        const int giy = (int)fy;
        const int giz = (int)fz;
        if (gix >= 0 && gix < kNX0 && giy >= 0 && giy < kNX1 && giz == 0)
            vox = gix * kNX1 + giy;
    }
    const float fc = feat_pv[(bn * kC + lane) * (kFH * kFW) + pixBase];
    const int outBase = (b * kC + lane) * (kNX0 * kNX1);
#pragma unroll 1
    for (int d = 0; d < kD; ++d) {
        const int   vd = __shfl(vox, d);
        const float wd = __shfl(wgt, d);
        if (vd >= 0)
            atomicAdd(&out[outBase + vd], wd * fc);
    }
}

extern "C" void kernel_launch(void* const* d_in, const int* in_sizes, int n_in,
                              void* d_out, int out_size, void* d_ws, size_t ws_size,
                              hipStream_t stream) {
    const float* feat_depth = (const float*)d_in[0];
    const float* feat_pv    = (const float*)d_in[1];
    const float* rots       = (const float*)d_in[2];
    const float* trans      = (const float*)d_in[3];
    const float* intrins    = (const float*)d_in[4];
    const float* post_rots  = (const float*)d_in[5];
    const float* post_trans = (const float*)d_in[6];
    float* out = (float*)d_out;

    if (ws_size < kWsNeed) {
        hipMemsetAsync(out, 0, (size_t)out_size * sizeof(float), stream);
        lss_scatter_fb<<<kPix / 4, 256, 0, stream>>>(
            feat_depth, feat_pv, rots, trans, intrins, post_rots, post_trans, out);
        return;
    }

    char* ws = (char*)d_ws;
    float*    pvT      = (float*)   (ws + kOffPvT);
    int*      voxArr   = (int*)     (ws + kOffVox);
    float*    wgtArr   = (float*)   (ws + kOffWgt);
    unsigned* counts   = (unsigned*)(ws + kOffCnt);
    unsigned* offsets  = (unsigned*)(ws + kOffOffs);
    unsigned* blockSums= (unsigned*)(ws + kOffBSum);
    unsigned* skey     = (unsigned*)(ws + kOffSKey);
    float*    swgt     = (float*)   (ws + kOffSWgt);

    lss_pvt<<<(kPvElems + 255) / 256, 256, 0, stream>>>(feat_pv, pvT, counts);
    lss_geom<<<kPix / 4, 256, 0, stream>>>(
        feat_depth, rots, trans, intrins, post_rots, post_trans,
        voxArr, wgtArr, counts);
    lss_scan_a<<<kScanBlks, 256, 0, stream>>>(counts, offsets, blockSums);
    lss_scan_b<<<1, 1024, 0, stream>>>(blockSums, offsets);
    lss_scan_c<<<kScanBlks, 256, 0, stream>>>(blockSums, offsets);
    lss_order<<<kPts / 256, 256, 0, stream>>>(voxArr, wgtArr, offsets, skey, swgt);
    lss_gather<<<kB * kNX0 * 4, 256, 0, stream>>>(pvT, offsets, skey, swgt, out);
}

// Round 5
// 178.593 us; speedup vs baseline: 3.8794x; 3.8794x over previous
//
#include <hip/hip_runtime.h>
#include <math.h>

namespace {
constexpr int kB = 4, kN = 6, kC = 64, kD = 41, kFH = 16, kFW = 44;
constexpr int kNX0 = 200, kNX1 = 200;
constexpr int kPix = kB * kN * kFH * kFW;          // 16896 pixels
constexpr int kPts = kPix * kD;                    // 692736 points
constexpr int kVox = kB * kNX0 * kNX1;             // 160000 voxels
constexpr int kPvElems = kPix * kC;                // 1081344
constexpr int kScanBlks = kVox / 256;              // 625 (exact)

// ws carve (all chunk sizes multiples of 8)
constexpr size_t kOffPvT    = 0;
constexpr size_t kSzPvT     = (size_t)kPvElems * 4;
constexpr size_t kOffVox    = kOffPvT + kSzPvT;
constexpr size_t kSzVox     = (size_t)kPts * 4;
constexpr size_t kOffWgt    = kOffVox + kSzVox;
constexpr size_t kSzWgt     = (size_t)kPts * 4;
constexpr size_t kOffCnt    = kOffWgt + kSzWgt;
constexpr size_t kSzCnt     = (size_t)kVox * 4;
constexpr size_t kOffOffs   = kOffCnt + kSzCnt;
constexpr size_t kSzOffs    = 640256;              // 160001 u32, padded
constexpr size_t kOffBSum   = kOffOffs + kSzOffs;
constexpr size_t kSzBSum    = 2560;                // 625 u32, padded
constexpr size_t kOffSKW    = kOffBSum + kSzBSum;
constexpr size_t kSzSKW     = (size_t)kPts * 8;    // uint2 (pix, wgt-bits)
constexpr size_t kWsNeed    = kOffSKW + kSzSKW + 256;
}

__device__ __forceinline__ void inv3x3(const float m[9], float inv[9]) {
    float a = m[0], b = m[1], c = m[2];
    float d = m[3], e = m[4], f = m[5];
    float g = m[6], h = m[7], i = m[8];
    float A =  (e * i - f * h);
    float Bm = -(d * i - f * g);
    float Cm =  (d * h - e * g);
    float det = a * A + b * Bm + c * Cm;
    float r = 1.0f / det;
    inv[0] = A * r;
    inv[1] = -(b * i - c * h) * r;
    inv[2] =  (b * f - c * e) * r;
    inv[3] = Bm * r;
    inv[4] =  (a * i - c * g) * r;
    inv[5] = -(a * f - c * d) * r;
    inv[6] = Cm * r;
    inv[7] = -(a * h - b * g) * r;
    inv[8] =  (a * e - b * d) * r;
}

// ---- K0: transpose feat_pv [bn,C,hw] -> pvT [pix][C]; also zero counts ----
__global__ __launch_bounds__(256) void lss_pvt(const float* __restrict__ pv,
                                               float* __restrict__ pvT,
                                               unsigned* __restrict__ counts) {
    int i = blockIdx.x * 256 + threadIdx.x;
    if (i < kPvElems) {
        int c = i & 63;
        int pix = i >> 6;
        int bn = pix / (kFH * kFW), hw = pix % (kFH * kFW);
        pvT[i] = pv[(bn * kC + c) * (kFH * kFW) + hw];
    }
    if (i < kVox) counts[i] = 0u;
}

// ---- K1: per-pixel softmax + geometry -> (vox, wgt) per point + histogram ----
__global__ __launch_bounds__(256) void lss_geom(
    const float* __restrict__ feat_depth,
    const float* __restrict__ rots,
    const float* __restrict__ trans,
    const float* __restrict__ intrins,
    const float* __restrict__ post_rots,
    const float* __restrict__ post_trans,
    int* __restrict__ voxArr, float* __restrict__ wgtArr,
    unsigned* __restrict__ counts)
{
    const int lane = threadIdx.x & 63;
    const int wave = threadIdx.x >> 6;
    const int pix  = blockIdx.x * 4 + wave;

    const int w  = pix % kFW;
    const int h  = (pix / kFW) % kFH;
    const int bn = pix / (kFW * kFH);
    const int b  = bn / kN;

    const float* R  = rots       + bn * 9;
    const float* K  = intrins    + bn * 9;
    const float* PR = post_rots  + bn * 9;
    const float* PT = post_trans + bn * 3;
    const float* T  = trans      + bn * 3;

    float Km[9], PRm[9];
#pragma unroll
    for (int i = 0; i < 9; ++i) { Km[i] = K[i]; PRm[i] = PR[i]; }
    float invK[9], invPR[9];
    inv3x3(Km, invK);
    inv3x3(PRm, invPR);
    float M[9];
#pragma unroll
    for (int i = 0; i < 3; ++i)
#pragma unroll
        for (int j = 0; j < 3; ++j)
            M[i * 3 + j] = R[i * 3 + 0] * invK[0 * 3 + j]
                         + R[i * 3 + 1] * invK[1 * 3 + j]
                         + R[i * 3 + 2] * invK[2 * 3 + j];
    const float pt0 = PT[0], pt1 = PT[1], pt2 = PT[2];
    const float t0 = T[0], t1 = T[1], t2 = T[2];

    const int pixBase = h * kFW + w;
    float fd = -INFINITY;
    if (lane < kD)
        fd = feat_depth[(bn * kD + lane) * (kFH * kFW) + pixBase];
    float mx = fd;
#pragma unroll
    for (int off = 32; off >= 1; off >>= 1)
        mx = fmaxf(mx, __shfl_xor(mx, off));
    float ex = (lane < kD) ? __expf(fd - mx) : 0.0f;
    float sm = ex;
#pragma unroll
    for (int off = 32; off >= 1; off >>= 1)
        sm += __shfl_xor(sm, off);
    const float wgt = ex / sm;

    if (lane < kD) {
        const float u  = (float)w * (703.0f / 43.0f);
        const float v  = (float)h * 17.0f;
        const float dv = 4.0f + (float)lane;
        const float px = u - pt0, py = v - pt1, pz = dv - pt2;
        const float ax = invPR[0] * px + invPR[1] * py + invPR[2] * pz;
        const float ay = invPR[3] * px + invPR[4] * py + invPR[5] * pz;
        const float az = invPR[6] * px + invPR[7] * py + invPR[8] * pz;
        const float qx = ax * az, qy = ay * az, qz = az;
        const float gx = M[0] * qx + M[1] * qy + M[2] * qz + t0;
        const float gy = M[3] * qx + M[4] * qy + M[5] * qz + t1;
        const float gz = M[6] * qx + M[7] * qy + M[8] * qz + t2;
        const float fx = (gx + 50.0f) / 0.5f;
        const float fy = (gy + 50.0f) / 0.5f;
        const float fz = (gz + 10.0f) / 20.0f;
        const int gix = (int)fx;
        const int giy = (int)fy;
        const int giz = (int)fz;
        int flat = -1;
        if (gix >= 0 && gix < kNX0 && giy >= 0 && giy < kNX1 && giz == 0) {
            flat = (b * kNX0 + gix) * kNX1 + giy;
            atomicAdd(&counts[flat], 1u);
        }
        const int p = pix * kD + lane;
        voxArr[p] = flat;
        wgtArr[p] = wgt;
    }
}

// ---- K2a: block-local exclusive scan (625 x 256, exact cover) ----
__global__ __launch_bounds__(256) void lss_scan_a(const unsigned* __restrict__ counts,
                                                  unsigned* __restrict__ offsets,
                                                  unsigned* __restrict__ blockSums) {
    const int i = blockIdx.x * 256 + threadIdx.x;
    const int lane = threadIdx.x & 63;
    const int wv = threadIdx.x >> 6;
    const unsigned c = counts[i];
    unsigned s = c;
#pragma unroll
    for (int o = 1; o < 64; o <<= 1) {
        unsigned v = __shfl_up(s, o);
        if (lane >= o) s += v;
    }
    __shared__ unsigned wsum[4];
    if (lane == 63) wsum[wv] = s;
    __syncthreads();
    unsigned base = 0;
#pragma unroll
    for (int k = 0; k < 3; ++k)
        if (k < wv) base += wsum[k];
    const unsigned incl = s + base;
    offsets[i] = incl - c;
    if (threadIdx.x == 255) blockSums[blockIdx.x] = incl;
}

// ---- K2b: scan 625 block sums (single block) ----
__global__ __launch_bounds__(1024) void lss_scan_b(unsigned* __restrict__ blockSums,
                                                   unsigned* __restrict__ offsets) {
    const int t = threadIdx.x;
    const int lane = t & 63;
    const int wv = t >> 6;
    const unsigned c = (t < kScanBlks) ? blockSums[t] : 0u;
    unsigned s = c;
#pragma unroll
    for (int o = 1; o < 64; o <<= 1) {
        unsigned v = __shfl_up(s, o);
        if (lane >= o) s += v;
    }
    __shared__ unsigned wsum[16];
    if (lane == 63) wsum[wv] = s;
    __syncthreads();
    unsigned base = 0;
#pragma unroll
    for (int k = 0; k < 15; ++k)
        if (k < wv) base += wsum[k];
    const unsigned incl = s + base;
    if (t < kScanBlks) blockSums[t] = incl - c;
    if (t == 1023) offsets[kVox] = incl;
}

// ---- K2c: add block base -> final exclusive offsets ----
__global__ __launch_bounds__(256) void lss_scan_c(const unsigned* __restrict__ blockSums,
                                                  unsigned* __restrict__ offsets) {
    const int i = blockIdx.x * 256 + threadIdx.x;
    offsets[i] += blockSums[blockIdx.x];
}

// ---- K3: scatter (pix, wgt) into CSR order; offsets doubles as cursor.
//      After this kernel, offsets[v] == end of segment v. ----
__global__ __launch_bounds__(256) void lss_order(const int* __restrict__ voxArr,
                                                 const float* __restrict__ wgtArr,
                                                 unsigned* __restrict__ offsets,
                                                 uint2* __restrict__ skw) {
    const int p = blockIdx.x * 256 + threadIdx.x;
    if (p < kPts) {
        const int f = voxArr[p];
        if (f >= 0) {
            const unsigned slot = atomicAdd(&offsets[f], 1u);
            uint2 u;
            u.x = (unsigned)(p / kD);                 // pix (< 16896)
            u.y = __float_as_uint(wgtArr[p]);
            skw[slot] = u;
        }
    }
}

// ---- K4: per-tile gather; register accumulate; broadcast uniform loads ----
__global__ __launch_bounds__(256) void lss_gather(const float* __restrict__ pvT,
                                                  const unsigned* __restrict__ offsets,
                                                  const uint2* __restrict__ skw,
                                                  float* __restrict__ out) {
    __shared__ float acc[50][65];
    const int tile = blockIdx.x;
    const int yt = tile & 3;
    const int xi = (tile >> 2) % kNX0;
    const int b  = tile / (kNX0 * 4);
    const int yi0 = yt * 50;
    const int lane = threadIdx.x & 63;
    const int wave = threadIdx.x >> 6;
    const int flat0 = (b * kNX0 + xi) * kNX1 + yi0;

    for (int j = wave; j < 50; j += 4) {
        const int flat = flat0 + j;
        const unsigned s0 = (flat == 0) ? 0u : offsets[flat - 1];  // end of prev == start
        const unsigned e0 = offsets[flat];                         // end of this voxel
        float a0 = 0.0f, a1 = 0.0f, a2 = 0.0f, a3 = 0.0f;
        unsigned p = s0;
        for (; p + 4u <= e0; p += 4u) {
            const uint2 u0 = skw[p + 0u];
            const uint2 u1 = skw[p + 1u];
            const uint2 u2 = skw[p + 2u];
            const uint2 u3 = skw[p + 3u];
            a0 += __uint_as_float(u0.y) * pvT[u0.x * kC + lane];
            a1 += __uint_as_float(u1.y) * pvT[u1.x * kC + lane];
            a2 += __uint_as_float(u2.y) * pvT[u2.x * kC + lane];
            a3 += __uint_as_float(u3.y) * pvT[u3.x * kC + lane];
        }
        for (; p < e0; ++p) {
            const uint2 u = skw[p];
            a0 += __uint_as_float(u.y) * pvT[u.x * kC + lane];
        }
        acc[j][lane] = (a0 + a1) + (a2 + a3);
    }
    __syncthreads();

    for (int e = threadIdx.x; e < kC * 50; e += 256) {
        const int c = e / 50, j = e % 50;
        out[((b * kC + c) * (kNX0 * kNX1)) + xi * kNX1 + yi0 + j] = acc[j][c];
    }
}

// ---- fallback: atomic path (used only if ws too small) ----
__global__ __launch_bounds__(256) void lss_scatter_fb(
    const float* __restrict__ feat_depth,
    const float* __restrict__ feat_pv,
    const float* __restrict__ rots,
    const float* __restrict__ trans,
    const float* __restrict__ intrins,
    const float* __restrict__ post_rots,
    const float* __restrict__ post_trans,
    float* __restrict__ out)
{
    const int lane = threadIdx.x & 63;
    const int wave = threadIdx.x >> 6;
    const int pix  = blockIdx.x * 4 + wave;
    const int w  = pix % kFW;
    const int h  = (pix / kFW) % kFH;
    const int bn = pix / (kFW * kFH);
    const int b  = bn / kN;
    const float* R  = rots       + bn * 9;
    const float* K  = intrins    + bn * 9;
    const float* PR = post_rots  + bn * 9;
    const float* PT = post_trans + bn * 3;
    const float* T  = trans      + bn * 3;
    float Km[9], PRm[9];
#pragma unroll
    for (int i = 0; i < 9; ++i) { Km[i] = K[i]; PRm[i] = PR[i]; }
    float invK[9], invPR[9];
    inv3x3(Km, invK);
    inv3x3(PRm, invPR);
    float M[9];
#pragma unroll
    for (int i = 0; i < 3; ++i)
#pragma unroll
        for (int j = 0; j < 3; ++j)
            M[i * 3 + j] = R[i * 3 + 0] * invK[0 * 3 + j]
                         + R[i * 3 + 1] * invK[1 * 3 + j]
                         + R[i * 3 + 2] * invK[2 * 3 + j];
    const float pt0 = PT[0], pt1 = PT[1], pt2 = PT[2];
    const float t0 = T[0], t1 = T[1], t2 = T[2];
    const int pixBase = h * kFW + w;
    float fd = -INFINITY;
    if (lane < kD)
        fd = feat_depth[(bn * kD + lane) * (kFH * kFW) + pixBase];
    float mx = fd;
#pragma unroll
    for (int off = 32; off >= 1; off >>= 1)
        mx = fmaxf(mx, __shfl_xor(mx, off));
    float ex = (lane < kD) ? __expf(fd - mx) : 0.0f;
    float sm = ex;
#pragma unroll
    for (int off = 32; off >= 1; off >>= 1)
        sm += __shfl_xor(sm, off);
    const float wgt = ex / sm;
    int vox = -1;
    if (lane < kD) {
        const float u  = (float)w * (703.0f / 43.0f);
        const float v  = (float)h * 17.0f;
        const float dv = 4.0f + (float)lane;
        const float px = u - pt0, py = v - pt1, pz = dv - pt2;
        const float ax = invPR[0] * px + invPR[1] * py + invPR[2] * pz;
        const float ay = invPR[3] * px + invPR[4] * py + invPR[5] * pz;
        const float az = invPR[6] * px + invPR[7] * py + invPR[8] * pz;
        const float qx = ax * az, qy = ay * az, qz = az;
        const float gx = M[0] * qx + M[1] * qy + M[2] * qz + t0;
        const float gy = M[3] * qx + M[4] * qy + M[5] * qz + t1;
        const float gz = M[6] * qx + M[7] * qy + M[8] * qz + t2;
        const float fx = (gx + 50.0f) / 0.5f;
        const float fy = (gy + 50.0f) / 0.5f;
        const float fz = (gz + 10.0f) / 20.0f;
        const int gix = (int)fx;
        const int giy = (int)fy;
        const int giz = (int)fz;
        if (gix >= 0 && gix < kNX0 && giy >= 0 && giy < kNX1 && giz == 0)
            vox = gix * kNX1 + giy;
    }
    const float fc = feat_pv[(bn * kC + lane) * (kFH * kFW) + pixBase];
    const int outBase = (b * kC + lane) * (kNX0 * kNX1);
#pragma unroll 1
    for (int d = 0; d < kD; ++d) {
        const int   vd = __shfl(vox, d);
        const float wd = __shfl(wgt, d);
        if (vd >= 0)
            atomicAdd(&out[outBase + vd], wd * fc);
    }
}

extern "C" void kernel_launch(void* const* d_in, const int* in_sizes, int n_in,
                              void* d_out, int out_size, void* d_ws, size_t ws_size,
                              hipStream_t stream) {
    const float* feat_depth = (const float*)d_in[0];
    const float* feat_pv    = (const float*)d_in[1];
    const float* rots       = (const float*)d_in[2];
    const float* trans      = (const float*)d_in[3];
    const float* intrins    = (const float*)d_in[4];
    const float* post_rots  = (const float*)d_in[5];
    const float* post_trans = (const float*)d_in[6];
    float* out = (float*)d_out;

    if (ws_size < kWsNeed) {
        hipMemsetAsync(out, 0, (size_t)out_size * sizeof(float), stream);
        lss_scatter_fb<<<kPix / 4, 256, 0, stream>>>(
            feat_depth, feat_pv, rots, trans, intrins, post_rots, post_trans, out);
        return;
    }

    char* ws = (char*)d_ws;
    float*    pvT      = (float*)   (ws + kOffPvT);
    int*      voxArr   = (int*)     (ws + kOffVox);
    float*    wgtArr   = (float*)   (ws + kOffWgt);
    unsigned* counts   = (unsigned*)(ws + kOffCnt);
    unsigned* offsets  = (unsigned*)(ws + kOffOffs);
    unsigned* blockSums= (unsigned*)(ws + kOffBSum);
    uint2*    skw      = (uint2*)   (ws + kOffSKW);

    lss_pvt<<<(kPvElems + 255) / 256, 256, 0, stream>>>(feat_pv, pvT, counts);
    lss_geom<<<kPix / 4, 256, 0, stream>>>(
        feat_depth, rots, trans, intrins, post_rots, post_trans,
        voxArr, wgtArr, counts);
    lss_scan_a<<<kScanBlks, 256, 0, stream>>>(counts, offsets, blockSums);
    lss_scan_b<<<1, 1024, 0, stream>>>(blockSums, offsets);
    lss_scan_c<<<kScanBlks, 256, 0, stream>>>(blockSums, offsets);
    lss_order<<<kPts / 256, 256, 0, stream>>>(voxArr, wgtArr, offsets, skw);
    lss_gather<<<kB * kNX0 * 4, 256, 0, stream>>>(pvT, offsets, skw, out);
}

// Round 6
// 154.853 us; speedup vs baseline: 4.4741x; 1.1533x over previous
//
#include <hip/hip_runtime.h>
#include <math.h>

namespace {
constexpr int kB = 4, kN = 6, kC = 64, kD = 41, kFH = 16, kFW = 44;
constexpr int kNX0 = 200, kNX1 = 200;
constexpr int kPix = kB * kN * kFH * kFW;          // 16896 pixels
constexpr int kPts = kPix * kD;                    // 692736 points
constexpr int kVox = kB * kNX0 * kNX1;             // 160000 voxels
constexpr int kPvElems = kPix * kC;                // 1081344
constexpr int kScanBlks = kVox / 256;              // 625 (exact)

// ws carve (all chunk sizes multiples of 8)
constexpr size_t kOffPvT    = 0;
constexpr size_t kSzPvT     = (size_t)kPvElems * 4;
constexpr size_t kOffVox    = kOffPvT + kSzPvT;
constexpr size_t kSzVox     = (size_t)kPts * 4;
constexpr size_t kOffWgt    = kOffVox + kSzVox;
constexpr size_t kSzWgt     = (size_t)kPts * 4;
constexpr size_t kOffCnt    = kOffWgt + kSzWgt;
constexpr size_t kSzCnt     = (size_t)kVox * 4;
constexpr size_t kOffOffs   = kOffCnt + kSzCnt;
constexpr size_t kSzOffs    = 640256;              // 160001 u32, padded
constexpr size_t kOffBSum   = kOffOffs + kSzOffs;
constexpr size_t kSzBSum    = 2560;                // 625 u32, padded
constexpr size_t kOffSKW    = kOffBSum + kSzBSum;
constexpr size_t kSzSKW     = (size_t)kPts * 8;    // uint2 (pix, wgt-bits)
constexpr size_t kWsNeed    = kOffSKW + kSzSKW + 256;
}

__device__ __forceinline__ void inv3x3(const float m[9], float inv[9]) {
    float a = m[0], b = m[1], c = m[2];
    float d = m[3], e = m[4], f = m[5];
    float g = m[6], h = m[7], i = m[8];
    float A =  (e * i - f * h);
    float Bm = -(d * i - f * g);
    float Cm =  (d * h - e * g);
    float det = a * A + b * Bm + c * Cm;
    float r = 1.0f / det;
    inv[0] = A * r;
    inv[1] = -(b * i - c * h) * r;
    inv[2] =  (b * f - c * e) * r;
    inv[3] = Bm * r;
    inv[4] =  (a * i - c * g) * r;
    inv[5] = -(a * f - c * d) * r;
    inv[6] = Cm * r;
    inv[7] = -(a * h - b * g) * r;
    inv[8] =  (a * e - b * d) * r;
}

// ---- K0: transpose feat_pv [bn,C,hw] -> pvT [pix][C]; also zero counts ----
__global__ __launch_bounds__(256) void lss_pvt(const float* __restrict__ pv,
                                               float* __restrict__ pvT,
                                               unsigned* __restrict__ counts) {
    int i = blockIdx.x * 256 + threadIdx.x;
    if (i < kPvElems) {
        int c = i & 63;
        int pix = i >> 6;
        int bn = pix / (kFH * kFW), hw = pix % (kFH * kFW);
        pvT[i] = pv[(bn * kC + c) * (kFH * kFW) + hw];
    }
    if (i < kVox) counts[i] = 0u;
}

// ---- K1: per-pixel softmax + geometry -> (vox, wgt) per point + histogram ----
__global__ __launch_bounds__(256) void lss_geom(
    const float* __restrict__ feat_depth,
    const float* __restrict__ rots,
    const float* __restrict__ trans,
    const float* __restrict__ intrins,
    const float* __restrict__ post_rots,
    const float* __restrict__ post_trans,
    int* __restrict__ voxArr, float* __restrict__ wgtArr,
    unsigned* __restrict__ counts)
{
    const int lane = threadIdx.x & 63;
    const int wave = threadIdx.x >> 6;
    const int pix  = blockIdx.x * 4 + wave;

    const int w  = pix % kFW;
    const int h  = (pix / kFW) % kFH;
    const int bn = pix / (kFW * kFH);
    const int b  = bn / kN;

    const float* R  = rots       + bn * 9;
    const float* K  = intrins    + bn * 9;
    const float* PR = post_rots  + bn * 9;
    const float* PT = post_trans + bn * 3;
    const float* T  = trans      + bn * 3;

    float Km[9], PRm[9];
#pragma unroll
    for (int i = 0; i < 9; ++i) { Km[i] = K[i]; PRm[i] = PR[i]; }
    float invK[9], invPR[9];
    inv3x3(Km, invK);
    inv3x3(PRm, invPR);
    float M[9];
#pragma unroll
    for (int i = 0; i < 3; ++i)
#pragma unroll
        for (int j = 0; j < 3; ++j)
            M[i * 3 + j] = R[i * 3 + 0] * invK[0 * 3 + j]
                         + R[i * 3 + 1] * invK[1 * 3 + j]
                         + R[i * 3 + 2] * invK[2 * 3 + j];
    const float pt0 = PT[0], pt1 = PT[1], pt2 = PT[2];
    const float t0 = T[0], t1 = T[1], t2 = T[2];

    const int pixBase = h * kFW + w;
    float fd = -INFINITY;
    if (lane < kD)
        fd = feat_depth[(bn * kD + lane) * (kFH * kFW) + pixBase];
    float mx = fd;
#pragma unroll
    for (int off = 32; off >= 1; off >>= 1)
        mx = fmaxf(mx, __shfl_xor(mx, off));
    float ex = (lane < kD) ? __expf(fd - mx) : 0.0f;
    float sm = ex;
#pragma unroll
    for (int off = 32; off >= 1; off >>= 1)
        sm += __shfl_xor(sm, off);
    const float wgt = ex / sm;

    if (lane < kD) {
        const float u  = (float)w * (703.0f / 43.0f);
        const float v  = (float)h * 17.0f;
        const float dv = 4.0f + (float)lane;
        const float px = u - pt0, py = v - pt1, pz = dv - pt2;
        const float ax = invPR[0] * px + invPR[1] * py + invPR[2] * pz;
        const float ay = invPR[3] * px + invPR[4] * py + invPR[5] * pz;
        const float az = invPR[6] * px + invPR[7] * py + invPR[8] * pz;
        const float qx = ax * az, qy = ay * az, qz = az;
        const float gx = M[0] * qx + M[1] * qy + M[2] * qz + t0;
        const float gy = M[3] * qx + M[4] * qy + M[5] * qz + t1;
        const float gz = M[6] * qx + M[7] * qy + M[8] * qz + t2;
        const float fx = (gx + 50.0f) / 0.5f;
        const float fy = (gy + 50.0f) / 0.5f;
        const float fz = (gz + 10.0f) / 20.0f;
        const int gix = (int)fx;
        const int giy = (int)fy;
        const int giz = (int)fz;
        int flat = -1;
        if (gix >= 0 && gix < kNX0 && giy >= 0 && giy < kNX1 && giz == 0) {
            flat = (b * kNX0 + gix) * kNX1 + giy;
            atomicAdd(&counts[flat], 1u);
        }
        const int p = pix * kD + lane;
        voxArr[p] = flat;
        wgtArr[p] = wgt;
    }
}

// ---- K2a: block-local exclusive scan (625 x 256, exact cover) ----
__global__ __launch_bounds__(256) void lss_scan_a(const unsigned* __restrict__ counts,
                                                  unsigned* __restrict__ offsets,
                                                  unsigned* __restrict__ blockSums) {
    const int i = blockIdx.x * 256 + threadIdx.x;
    const int lane = threadIdx.x & 63;
    const int wv = threadIdx.x >> 6;
    const unsigned c = counts[i];
    unsigned s = c;
#pragma unroll
    for (int o = 1; o < 64; o <<= 1) {
        unsigned v = __shfl_up(s, o);
        if (lane >= o) s += v;
    }
    __shared__ unsigned wsum[4];
    if (lane == 63) wsum[wv] = s;
    __syncthreads();
    unsigned base = 0;
#pragma unroll
    for (int k = 0; k < 3; ++k)
        if (k < wv) base += wsum[k];
    const unsigned incl = s + base;
    offsets[i] = incl - c;
    if (threadIdx.x == 255) blockSums[blockIdx.x] = incl;
}

// ---- K2b: scan 625 block sums (single block) ----
__global__ __launch_bounds__(1024) void lss_scan_b(unsigned* __restrict__ blockSums,
                                                   unsigned* __restrict__ offsets) {
    const int t = threadIdx.x;
    const int lane = t & 63;
    const int wv = t >> 6;
    const unsigned c = (t < kScanBlks) ? blockSums[t] : 0u;
    unsigned s = c;
#pragma unroll
    for (int o = 1; o < 64; o <<= 1) {
        unsigned v = __shfl_up(s, o);
        if (lane >= o) s += v;
    }
    __shared__ unsigned wsum[16];
    if (lane == 63) wsum[wv] = s;
    __syncthreads();
    unsigned base = 0;
#pragma unroll
    for (int k = 0; k < 15; ++k)
        if (k < wv) base += wsum[k];
    const unsigned incl = s + base;
    if (t < kScanBlks) blockSums[t] = incl - c;
    if (t == 1023) offsets[kVox] = incl;
}

// ---- K2c: add block base -> final exclusive offsets ----
__global__ __launch_bounds__(256) void lss_scan_c(const unsigned* __restrict__ blockSums,
                                                  unsigned* __restrict__ offsets) {
    const int i = blockIdx.x * 256 + threadIdx.x;
    offsets[i] += blockSums[blockIdx.x];
}

// ---- K3: scatter (pix, wgt) into CSR order; offsets doubles as cursor.
//      After this kernel, offsets[v] == end of segment v. ----
__global__ __launch_bounds__(256) void lss_order(const int* __restrict__ voxArr,
                                                 const float* __restrict__ wgtArr,
                                                 unsigned* __restrict__ offsets,
                                                 uint2* __restrict__ skw) {
    const int p = blockIdx.x * 256 + threadIdx.x;
    if (p < kPts) {
        const int f = voxArr[p];
        if (f >= 0) {
            const unsigned slot = atomicAdd(&offsets[f], 1u);
            uint2 u;
            u.x = (unsigned)(p / kD);                 // pix (< 16896)
            u.y = __float_as_uint(wgtArr[p]);
            skw[slot] = u;
        }
    }
}

// ---- K4: per-tile gather; LDS-staged CSR segment; register accumulate ----
__global__ __launch_bounds__(256) void lss_gather(const float* __restrict__ pvT,
                                                  const unsigned* __restrict__ offsets,
                                                  const uint2* __restrict__ skw,
                                                  float* __restrict__ out) {
    constexpr int kChunk = 2048;                   // 16 KB staging buffer
    __shared__ float acc[50][65];
    __shared__ uint2 sbuf[kChunk];
    const int tile = blockIdx.x;
    const int yt = tile & 3;
    const int xi = (tile >> 2) % kNX0;
    const int b  = tile / (kNX0 * 4);
    const int yi0 = yt * 50;
    const int lane = threadIdx.x & 63;
    const int wave = threadIdx.x >> 6;
    const int flat0 = (b * kNX0 + xi) * kNX1 + yi0;

    for (int e = threadIdx.x; e < 50 * 65; e += 256)
        ((float*)acc)[e] = 0.0f;

    const unsigned seg0 = (flat0 == 0) ? 0u : offsets[flat0 - 1];  // end prev == start
    const unsigned seg1 = offsets[flat0 + 49];                     // end of tile

    for (unsigned cb = seg0; cb < seg1; cb += (unsigned)kChunk) {
        const unsigned ce = min(cb + (unsigned)kChunk, seg1);
        const int n = (int)(ce - cb);
        __syncthreads();                           // sbuf safe to overwrite
        for (int e = threadIdx.x; e < n; e += 256)
            sbuf[e] = skw[cb + e];
        __syncthreads();

        for (int j = wave; j < 50; j += 4) {
            const int flat = flat0 + j;
            unsigned s0 = (flat == 0) ? 0u : offsets[flat - 1];
            unsigned e0 = offsets[flat];
            s0 = max(s0, cb);
            e0 = min(e0, ce);
            if (s0 >= e0) continue;
            float a0 = 0.0f, a1 = 0.0f, a2 = 0.0f, a3 = 0.0f;
            int p  = (int)(s0 - cb);
            int pe = (int)(e0 - cb);
            for (; p + 4 <= pe; p += 4) {
                const uint2 u0 = sbuf[p + 0];
                const uint2 u1 = sbuf[p + 1];
                const uint2 u2 = sbuf[p + 2];
                const uint2 u3 = sbuf[p + 3];
                a0 += __uint_as_float(u0.y) * pvT[u0.x * kC + lane];
                a1 += __uint_as_float(u1.y) * pvT[u1.x * kC + lane];
                a2 += __uint_as_float(u2.y) * pvT[u2.x * kC + lane];
                a3 += __uint_as_float(u3.y) * pvT[u3.x * kC + lane];
            }
            for (; p < pe; ++p) {
                const uint2 u = sbuf[p];
                a0 += __uint_as_float(u.y) * pvT[u.x * kC + lane];
            }
            acc[j][lane] += (a0 + a1) + (a2 + a3);
        }
    }
    __syncthreads();

    for (int e = threadIdx.x; e < kC * 50; e += 256) {
        const int c = e / 50, j = e % 50;
        out[((b * kC + c) * (kNX0 * kNX1)) + xi * kNX1 + yi0 + j] = acc[j][c];
    }
}

// ---- fallback: atomic path (used only if ws too small) ----
__global__ __launch_bounds__(256) void lss_scatter_fb(
    const float* __restrict__ feat_depth,
    const float* __restrict__ feat_pv,
    const float* __restrict__ rots,
    const float* __restrict__ trans,
    const float* __restrict__ intrins,
    const float* __restrict__ post_rots,
    const float* __restrict__ post_trans,
    float* __restrict__ out)
{
    const int lane = threadIdx.x & 63;
    const int wave = threadIdx.x >> 6;
    const int pix  = blockIdx.x * 4 + wave;
    const int w  = pix % kFW;
    const int h  = (pix / kFW) % kFH;
    const int bn = pix / (kFW * kFH);
    const int b  = bn / kN;
    const float* R  = rots       + bn * 9;
    const float* K  = intrins    + bn * 9;
    const float* PR = post_rots  + bn * 9;
    const float* PT = post_trans + bn * 3;
    const float* T  = trans      + bn * 3;
    float Km[9], PRm[9];
#pragma unroll
    for (int i = 0; i < 9; ++i) { Km[i] = K[i]; PRm[i] = PR[i]; }
    float invK[9], invPR[9];
    inv3x3(Km, invK);
    inv3x3(PRm, invPR);
    float M[9];
#pragma unroll
    for (int i = 0; i < 3; ++i)
#pragma unroll
        for (int j = 0; j < 3; ++j)
            M[i * 3 + j] = R[i * 3 + 0] * invK[0 * 3 + j]
                         + R[i * 3 + 1] * invK[1 * 3 + j]
                         + R[i * 3 + 2] * invK[2 * 3 + j];
    const float pt0 = PT[0], pt1 = PT[1], pt2 = PT[2];
    const float t0 = T[0], t1 = T[1], t2 = T[2];
    const int pixBase = h * kFW + w;
    float fd = -INFINITY;
    if (lane < kD)
        fd = feat_depth[(bn * kD + lane) * (kFH * kFW) + pixBase];
    float mx = fd;
#pragma unroll
    for (int off = 32; off >= 1; off >>= 1)
        mx = fmaxf(mx, __shfl_xor(mx, off));
    float ex = (lane < kD) ? __expf(fd - mx) : 0.0f;
    float sm = ex;
#pragma unroll
    for (int off = 32; off >= 1; off >>= 1)
        sm += __shfl_xor(sm, off);
    const float wgt = ex / sm;
    int vox = -1;
    if (lane < kD) {
        const float u  = (float)w * (703.0f / 43.0f);
        const float v  = (float)h * 17.0f;
        const float dv = 4.0f + (float)lane;
        const float px = u - pt0, py = v - pt1, pz = dv - pt2;
        const float ax = invPR[0] * px + invPR[1] * py + invPR[2] * pz;
        const float ay = invPR[3] * px + invPR[4] * py + invPR[5] * pz;
        const float az = invPR[6] * px + invPR[7] * py + invPR[8] * pz;
        const float qx = ax * az, qy = ay * az, qz = az;
        const float gx = M[0] * qx + M[1] * qy + M[2] * qz + t0;
        const float gy = M[3] * qx + M[4] * qy + M[5] * qz + t1;
        const float gz = M[6] * qx + M[7] * qy + M[8] * qz + t2;
        const float fx = (gx + 50.0f) / 0.5f;
        const float fy = (gy + 50.0f) / 0.5f;
        const float fz = (gz + 10.0f) / 20.0f;
        const int gix = (int)fx;
        const int giy = (int)fy;
        const int giz = (int)fz;
        if (gix >= 0 && gix < kNX0 && giy >= 0 && giy < kNX1 && giz == 0)
            vox = gix * kNX1 + giy;
    }
    const float fc = feat_pv[(bn * kC + lane) * (kFH * kFW) + pixBase];
    const int outBase = (b * kC + lane) * (kNX0 * kNX1);
#pragma unroll 1
    for (int d = 0; d < kD; ++d) {
        const int   vd = __shfl(vox, d);
        const float wd = __shfl(wgt, d);
        if (vd >= 0)
            atomicAdd(&out[outBase + vd], wd * fc);
    }
}

extern "C" void kernel_launch(void* const* d_in, const int* in_sizes, int n_in,
                              void* d_out, int out_size, void* d_ws, size_t ws_size,
                              hipStream_t stream) {
    const float* feat_depth = (const float*)d_in[0];
    const float* feat_pv    = (const float*)d_in[1];
    const float* rots       = (const float*)d_in[2];
    const float* trans      = (const float*)d_in[3];
    const float* intrins    = (const float*)d_in[4];
    const float* post_rots  = (const float*)d_in[5];
    const float* post_trans = (const float*)d_in[6];
    float* out = (float*)d_out;

    if (ws_size < kWsNeed) {
        hipMemsetAsync(out, 0, (size_t)out_size * sizeof(float), stream);
        lss_scatter_fb<<<kPix / 4, 256, 0, stream>>>(
            feat_depth, feat_pv, rots, trans, intrins, post_rots, post_trans, out);
        return;
    }

    char* ws = (char*)d_ws;
    float*    pvT      = (float*)   (ws + kOffPvT);
    int*      voxArr   = (int*)     (ws + kOffVox);
    float*    wgtArr   = (float*)   (ws + kOffWgt);
    unsigned* counts   = (unsigned*)(ws + kOffCnt);
    unsigned* offsets  = (unsigned*)(ws + kOffOffs);
    unsigned* blockSums= (unsigned*)(ws + kOffBSum);
    uint2*    skw      = (uint2*)   (ws + kOffSKW);

    lss_pvt<<<(kPvElems + 255) / 256, 256, 0, stream>>>(feat_pv, pvT, counts);
    lss_geom<<<kPix / 4, 256, 0, stream>>>(
        feat_depth, rots, trans, intrins, post_rots, post_trans,
        voxArr, wgtArr, counts);
    lss_scan_a<<<kScanBlks, 256, 0, stream>>>(counts, offsets, blockSums);
    lss_scan_b<<<1, 1024, 0, stream>>>(blockSums, offsets);
    lss_scan_c<<<kScanBlks, 256, 0, stream>>>(blockSums, offsets);
    lss_order<<<kPts / 256, 256, 0, stream>>>(voxArr, wgtArr, offsets, skw);
    lss_gather<<<kB * kNX0 * 4, 256, 0, stream>>>(pvT, offsets, skw, out);
}

// Round 7
// 133.652 us; speedup vs baseline: 5.1838x; 1.1586x over previous
//
#include <hip/hip_runtime.h>
#include <math.h>

namespace {
constexpr int kB = 4, kN = 6, kC = 64, kD = 41, kFH = 16, kFW = 44;
constexpr int kNX0 = 200, kNX1 = 200;
constexpr int kPix = kB * kN * kFH * kFW;          // 16896 pixels
constexpr int kPts = kPix * kD;                    // 692736 points
constexpr int kVox = kB * kNX0 * kNX1;             // 160000 voxels
constexpr int kPvElems = kPix * kC;                // 1081344
constexpr int kScanBlks = kVox / 256;              // 625 (exact)

// ws carve (all chunk sizes multiples of 8)
constexpr size_t kOffPvT    = 0;
constexpr size_t kSzPvT     = (size_t)kPvElems * 4;
constexpr size_t kOffVox    = kOffPvT + kSzPvT;
constexpr size_t kSzVox     = (size_t)kPts * 4;
constexpr size_t kOffWgt    = kOffVox + kSzVox;
constexpr size_t kSzWgt     = (size_t)kPts * 4;
constexpr size_t kOffCnt    = kOffWgt + kSzWgt;
constexpr size_t kSzCnt     = (size_t)kVox * 4;
constexpr size_t kOffOffs   = kOffCnt + kSzCnt;
constexpr size_t kSzOffs    = 640256;              // 160001 u32, padded
constexpr size_t kOffBSum   = kOffOffs + kSzOffs;
constexpr size_t kSzBSum    = 2560;                // 625 u32, padded
constexpr size_t kOffSKW    = kOffBSum + kSzBSum;
constexpr size_t kSzSKW     = (size_t)kPts * 8;    // uint2 (pix, wgt-bits)
constexpr size_t kWsNeed    = kOffSKW + kSzSKW + 256;
}

__device__ __forceinline__ void inv3x3(const float m[9], float inv[9]) {
    float a = m[0], b = m[1], c = m[2];
    float d = m[3], e = m[4], f = m[5];
    float g = m[6], h = m[7], i = m[8];
    float A =  (e * i - f * h);
    float Bm = -(d * i - f * g);
    float Cm =  (d * h - e * g);
    float det = a * A + b * Bm + c * Cm;
    float r = 1.0f / det;
    inv[0] = A * r;
    inv[1] = -(b * i - c * h) * r;
    inv[2] =  (b * f - c * e) * r;
    inv[3] = Bm * r;
    inv[4] =  (a * i - c * g) * r;
    inv[5] = -(a * f - c * d) * r;
    inv[6] = Cm * r;
    inv[7] = -(a * h - b * g) * r;
    inv[8] =  (a * e - b * d) * r;
}

// ---- K0: transpose feat_pv [bn,C,hw] -> pvT [pix][C]; also zero counts ----
__global__ __launch_bounds__(256) void lss_pvt(const float* __restrict__ pv,
                                               float* __restrict__ pvT,
                                               unsigned* __restrict__ counts) {
    int i = blockIdx.x * 256 + threadIdx.x;
    if (i < kPvElems) {
        int c = i & 63;
        int pix = i >> 6;
        int bn = pix / (kFH * kFW), hw = pix % (kFH * kFW);
        pvT[i] = pv[(bn * kC + c) * (kFH * kFW) + hw];
    }
    if (i < kVox) counts[i] = 0u;
}

// ---- K1: per-pixel softmax + geometry -> (vox, wgt) per point + histogram ----
__global__ __launch_bounds__(256) void lss_geom(
    const float* __restrict__ feat_depth,
    const float* __restrict__ rots,
    const float* __restrict__ trans,
    const float* __restrict__ intrins,
    const float* __restrict__ post_rots,
    const float* __restrict__ post_trans,
    int* __restrict__ voxArr, float* __restrict__ wgtArr,
    unsigned* __restrict__ counts)
{
    const int lane = threadIdx.x & 63;
    const int wave = threadIdx.x >> 6;
    const int pix  = blockIdx.x * 4 + wave;

    const int w  = pix % kFW;
    const int h  = (pix / kFW) % kFH;
    const int bn = pix / (kFW * kFH);
    const int b  = bn / kN;

    const float* R  = rots       + bn * 9;
    const float* K  = intrins    + bn * 9;
    const float* PR = post_rots  + bn * 9;
    const float* PT = post_trans + bn * 3;
    const float* T  = trans      + bn * 3;

    float Km[9], PRm[9];
#pragma unroll
    for (int i = 0; i < 9; ++i) { Km[i] = K[i]; PRm[i] = PR[i]; }
    float invK[9], invPR[9];
    inv3x3(Km, invK);
    inv3x3(PRm, invPR);
    float M[9];
#pragma unroll
    for (int i = 0; i < 3; ++i)
#pragma unroll
        for (int j = 0; j < 3; ++j)
            M[i * 3 + j] = R[i * 3 + 0] * invK[0 * 3 + j]
                         + R[i * 3 + 1] * invK[1 * 3 + j]
                         + R[i * 3 + 2] * invK[2 * 3 + j];
    const float pt0 = PT[0], pt1 = PT[1], pt2 = PT[2];
    const float t0 = T[0], t1 = T[1], t2 = T[2];

    const int pixBase = h * kFW + w;
    float fd = -INFINITY;
    if (lane < kD)
        fd = feat_depth[(bn * kD + lane) * (kFH * kFW) + pixBase];
    float mx = fd;
#pragma unroll
    for (int off = 32; off >= 1; off >>= 1)
        mx = fmaxf(mx, __shfl_xor(mx, off));
    float ex = (lane < kD) ? __expf(fd - mx) : 0.0f;
    float sm = ex;
#pragma unroll
    for (int off = 32; off >= 1; off >>= 1)
        sm += __shfl_xor(sm, off);
    const float wgt = ex / sm;

    if (lane < kD) {
        const float u  = (float)w * (703.0f / 43.0f);
        const float v  = (float)h * 17.0f;
        const float dv = 4.0f + (float)lane;
        const float px = u - pt0, py = v - pt1, pz = dv - pt2;
        const float ax = invPR[0] * px + invPR[1] * py + invPR[2] * pz;
        const float ay = invPR[3] * px + invPR[4] * py + invPR[5] * pz;
        const float az = invPR[6] * px + invPR[7] * py + invPR[8] * pz;
        const float qx = ax * az, qy = ay * az, qz = az;
        const float gx = M[0] * qx + M[1] * qy + M[2] * qz + t0;
        const float gy = M[3] * qx + M[4] * qy + M[5] * qz + t1;
        const float gz = M[6] * qx + M[7] * qy + M[8] * qz + t2;
        const float fx = (gx + 50.0f) / 0.5f;
        const float fy = (gy + 50.0f) / 0.5f;
        const float fz = (gz + 10.0f) / 20.0f;
        const int gix = (int)fx;
        const int giy = (int)fy;
        const int giz = (int)fz;
        int flat = -1;
        if (gix >= 0 && gix < kNX0 && giy >= 0 && giy < kNX1 && giz == 0) {
            flat = (b * kNX0 + gix) * kNX1 + giy;
            atomicAdd(&counts[flat], 1u);
        }
        const int p = pix * kD + lane;
        voxArr[p] = flat;
        wgtArr[p] = wgt;
    }
}

// ---- K2a: block-local exclusive scan (625 x 256, exact cover) ----
__global__ __launch_bounds__(256) void lss_scan_a(const unsigned* __restrict__ counts,
                                                  unsigned* __restrict__ offsets,
                                                  unsigned* __restrict__ blockSums) {
    const int i = blockIdx.x * 256 + threadIdx.x;
    const int lane = threadIdx.x & 63;
    const int wv = threadIdx.x >> 6;
    const unsigned c = counts[i];
    unsigned s = c;
#pragma unroll
    for (int o = 1; o < 64; o <<= 1) {
        unsigned v = __shfl_up(s, o);
        if (lane >= o) s += v;
    }
    __shared__ unsigned wsum[4];
    if (lane == 63) wsum[wv] = s;
    __syncthreads();
    unsigned base = 0;
#pragma unroll
    for (int k = 0; k < 3; ++k)
        if (k < wv) base += wsum[k];
    const unsigned incl = s + base;
    offsets[i] = incl - c;
    if (threadIdx.x == 255) blockSums[blockIdx.x] = incl;
}

// ---- K2b: scan 625 block sums (single block) ----
__global__ __launch_bounds__(1024) void lss_scan_b(unsigned* __restrict__ blockSums,
                                                   unsigned* __restrict__ offsets) {
    const int t = threadIdx.x;
    const int lane = t & 63;
    const int wv = t >> 6;
    const unsigned c = (t < kScanBlks) ? blockSums[t] : 0u;
    unsigned s = c;
#pragma unroll
    for (int o = 1; o < 64; o <<= 1) {
        unsigned v = __shfl_up(s, o);
        if (lane >= o) s += v;
    }
    __shared__ unsigned wsum[16];
    if (lane == 63) wsum[wv] = s;
    __syncthreads();
    unsigned base = 0;
#pragma unroll
    for (int k = 0; k < 15; ++k)
        if (k < wv) base += wsum[k];
    const unsigned incl = s + base;
    if (t < kScanBlks) blockSums[t] = incl - c;
    if (t == 1023) offsets[kVox] = incl;
}

// ---- K2c: add block base -> final exclusive offsets ----
__global__ __launch_bounds__(256) void lss_scan_c(const unsigned* __restrict__ blockSums,
                                                  unsigned* __restrict__ offsets) {
    const int i = blockIdx.x * 256 + threadIdx.x;
    offsets[i] += blockSums[blockIdx.x];
}

// ---- K3: scatter (pix, wgt) into CSR order; offsets doubles as cursor.
//      After this kernel, offsets[v] == end of segment v. ----
__global__ __launch_bounds__(256) void lss_order(const int* __restrict__ voxArr,
                                                 const float* __restrict__ wgtArr,
                                                 unsigned* __restrict__ offsets,
                                                 uint2* __restrict__ skw) {
    const int p = blockIdx.x * 256 + threadIdx.x;
    if (p < kPts) {
        const int f = voxArr[p];
        if (f >= 0) {
            const unsigned slot = atomicAdd(&offsets[f], 1u);
            uint2 u;
            u.x = (unsigned)(p / kD);                 // pix (< 16896)
            u.y = __float_as_uint(wgtArr[p]);
            skw[slot] = u;
        }
    }
}

// ---- K4: per-tile gather; LDS-staged CSR segment; register accumulate.
//      512 threads (8 waves) per block: wave cap = LDS cap -> full occupancy. ----
__global__ __launch_bounds__(512) void lss_gather(const float* __restrict__ pvT,
                                                  const unsigned* __restrict__ offsets,
                                                  const uint2* __restrict__ skw,
                                                  float* __restrict__ out) {
    constexpr int kChunk = 2048;                   // 16 KB staging buffer
    __shared__ float acc[50][65];                  // 13 KB
    __shared__ uint2 sbuf[kChunk];                 // 16 KB
    __shared__ unsigned rowOff[51];                // CSR bounds for the 50 rows
    const int tile = blockIdx.x;                   // b*800 + xi*4 + yt  (3200 total)
    const int yt = tile & 3;
    const int xi = (tile >> 2) % kNX0;
    const int b  = tile / (kNX0 * 4);
    const int yi0 = yt * 50;
    const int lane = threadIdx.x & 63;
    const int wave = threadIdx.x >> 6;             // 0..7
    const int flat0 = (b * kNX0 + xi) * kNX1 + yi0;

    for (int e = threadIdx.x; e < 50 * 65; e += 512)
        ((float*)acc)[e] = 0.0f;
    if (threadIdx.x < 51) {
        const int f = flat0 - 1 + (int)threadIdx.x;
        rowOff[threadIdx.x] = (f < 0) ? 0u : offsets[f];   // rowOff[j] = start of row j
    }
    __syncthreads();

    const unsigned seg0 = rowOff[0];
    const unsigned seg1 = rowOff[50];

    for (unsigned cb = seg0; cb < seg1; cb += (unsigned)kChunk) {
        const unsigned ce = min(cb + (unsigned)kChunk, seg1);
        const int n = (int)(ce - cb);
        for (int e = threadIdx.x; e < n; e += 512)
            sbuf[e] = skw[cb + e];
        __syncthreads();

        for (int j = wave; j < 50; j += 8) {
            unsigned s0 = max(rowOff[j], cb);
            unsigned e0 = min(rowOff[j + 1], ce);
            if (s0 >= e0) continue;
            float a0 = 0.0f, a1 = 0.0f, a2 = 0.0f, a3 = 0.0f;
            int p  = (int)(s0 - cb);
            int pe = (int)(e0 - cb);
            for (; p + 4 <= pe; p += 4) {
                const uint2 u0 = sbuf[p + 0];
                const uint2 u1 = sbuf[p + 1];
                const uint2 u2 = sbuf[p + 2];
                const uint2 u3 = sbuf[p + 3];
                a0 += __uint_as_float(u0.y) * pvT[u0.x * kC + lane];
                a1 += __uint_as_float(u1.y) * pvT[u1.x * kC + lane];
                a2 += __uint_as_float(u2.y) * pvT[u2.x * kC + lane];
                a3 += __uint_as_float(u3.y) * pvT[u3.x * kC + lane];
            }
            for (; p < pe; ++p) {
                const uint2 u = sbuf[p];
                a0 += __uint_as_float(u.y) * pvT[u.x * kC + lane];
            }
            acc[j][lane] += (a0 + a1) + (a2 + a3);
        }
        __syncthreads();                           // sbuf safe to overwrite next iter
    }
    __syncthreads();

    for (int e = threadIdx.x; e < kC * 50; e += 512) {
        const int c = e / 50, j = e % 50;
        out[((b * kC + c) * (kNX0 * kNX1)) + xi * kNX1 + yi0 + j] = acc[j][c];
    }
}

// ---- fallback: atomic path (used only if ws too small) ----
__global__ __launch_bounds__(256) void lss_scatter_fb(
    const float* __restrict__ feat_depth,
    const float* __restrict__ feat_pv,
    const float* __restrict__ rots,
    const float* __restrict__ trans,
    const float* __restrict__ intrins,
    const float* __restrict__ post_rots,
    const float* __restrict__ post_trans,
    float* __restrict__ out)
{
    const int lane = threadIdx.x & 63;
    const int wave = threadIdx.x >> 6;
    const int pix  = blockIdx.x * 4 + wave;
    const int w  = pix % kFW;
    const int h  = (pix / kFW) % kFH;
    const int bn = pix / (kFW * kFH);
    const int b  = bn / kN;
    const float* R  = rots       + bn * 9;
    const float* K  = intrins    + bn * 9;
    const float* PR = post_rots  + bn * 9;
    const float* PT = post_trans + bn * 3;
    const float* T  = trans      + bn * 3;
    float Km[9], PRm[9];
#pragma unroll
    for (int i = 0; i < 9; ++i) { Km[i] = K[i]; PRm[i] = PR[i]; }
    float invK[9], invPR[9];
    inv3x3(Km, invK);
    inv3x3(PRm, invPR);
    float M[9];
#pragma unroll
    for (int i = 0; i < 3; ++i)
#pragma unroll
        for (int j = 0; j < 3; ++j)
            M[i * 3 + j] = R[i * 3 + 0] * invK[0 * 3 + j]
                         + R[i * 3 + 1] * invK[1 * 3 + j]
                         + R[i * 3 + 2] * invK[2 * 3 + j];
    const float pt0 = PT[0], pt1 = PT[1], pt2 = PT[2];
    const float t0 = T[0], t1 = T[1], t2 = T[2];
    const int pixBase = h * kFW + w;
    float fd = -INFINITY;
    if (lane < kD)
        fd = feat_depth[(bn * kD + lane) * (kFH * kFW) + pixBase];
    float mx = fd;
#pragma unroll
    for (int off = 32; off >= 1; off >>= 1)
        mx = fmaxf(mx, __shfl_xor(mx, off));
    float ex = (lane < kD) ? __expf(fd - mx) : 0.0f;
    float sm = ex;
#pragma unroll
    for (int off = 32; off >= 1; off >>= 1)
        sm += __shfl_xor(sm, off);
    const float wgt = ex / sm;
    int vox = -1;
    if (lane < kD) {
        const float u  = (float)w * (703.0f / 43.0f);
        const float v  = (float)h * 17.0f;
        const float dv = 4.0f + (float)lane;
        const float px = u - pt0, py = v - pt1, pz = dv - pt2;
        const float ax = invPR[0] * px + invPR[1] * py + invPR[2] * pz;
        const float ay = invPR[3] * px + invPR[4] * py + invPR[5] * pz;
        const float az = invPR[6] * px + invPR[7] * py + invPR[8] * pz;
        const float qx = ax * az, qy = ay * az, qz = az;
        const float gx = M[0] * qx + M[1] * qy + M[2] * qz + t0;
        const float gy = M[3] * qx + M[4] * qy + M[5] * qz + t1;
        const float gz = M[6] * qx + M[7] * qy + M[8] * qz + t2;
        const float fx = (gx + 50.0f) / 0.5f;
        const float fy = (gy + 50.0f) / 0.5f;
        const float fz = (gz + 10.0f) / 20.0f;
        const int gix = (int)fx;
        const int giy = (int)fy;
        const int giz = (int)fz;
        if (gix >= 0 && gix < kNX0 && giy >= 0 && giy < kNX1 && giz == 0)
            vox = gix * kNX1 + giy;
    }
    const float fc = feat_pv[(bn * kC + lane) * (kFH * kFW) + pixBase];
    const int outBase = (b * kC + lane) * (kNX0 * kNX1);
#pragma unroll 1
    for (int d = 0; d < kD; ++d) {
        const int   vd = __shfl(vox, d);
        const float wd = __shfl(wgt, d);
        if (vd >= 0)
            atomicAdd(&out[outBase + vd], wd * fc);
    }
}

extern "C" void kernel_launch(void* const* d_in, const int* in_sizes, int n_in,
                              void* d_out, int out_size, void* d_ws, size_t ws_size,
                              hipStream_t stream) {
    const float* feat_depth = (const float*)d_in[0];
    const float* feat_pv    = (const float*)d_in[1];
    const float* rots       = (const float*)d_in[2];
    const float* trans      = (const float*)d_in[3];
    const float* intrins    = (const float*)d_in[4];
    const float* post_rots  = (const float*)d_in[5];
    const float* post_trans = (const float*)d_in[6];
    float* out = (float*)d_out;

    if (ws_size < kWsNeed) {
        hipMemsetAsync(out, 0, (size_t)out_size * sizeof(float), stream);
        lss_scatter_fb<<<kPix / 4, 256, 0, stream>>>(
            feat_depth, feat_pv, rots, trans, intrins, post_rots, post_trans, out);
        return;
    }

    char* ws = (char*)d_ws;
    float*    pvT      = (float*)   (ws + kOffPvT);
    int*      voxArr   = (int*)     (ws + kOffVox);
    float*    wgtArr   = (float*)   (ws + kOffWgt);
    unsigned* counts   = (unsigned*)(ws + kOffCnt);
    unsigned* offsets  = (unsigned*)(ws + kOffOffs);
    unsigned* blockSums= (unsigned*)(ws + kOffBSum);
    uint2*    skw      = (uint2*)   (ws + kOffSKW);

    lss_pvt<<<(kPvElems + 255) / 256, 256, 0, stream>>>(feat_pv, pvT, counts);
    lss_geom<<<kPix / 4, 256, 0, stream>>>(
        feat_depth, rots, trans, intrins, post_rots, post_trans,
        voxArr, wgtArr, counts);
    lss_scan_a<<<kScanBlks, 256, 0, stream>>>(counts, offsets, blockSums);
    lss_scan_b<<<1, 1024, 0, stream>>>(blockSums, offsets);
    lss_scan_c<<<kScanBlks, 256, 0, stream>>>(blockSums, offsets);
    lss_order<<<kPts / 256, 256, 0, stream>>>(voxArr, wgtArr, offsets, skw);
    lss_gather<<<kB * kNX0 * 4, 512, 0, stream>>>(pvT, offsets, skw, out);
}

// Round 8
// 117.896 us; speedup vs baseline: 5.8766x; 1.1336x over previous
//
#include <hip/hip_runtime.h>
#include <math.h>

namespace {
constexpr int kB = 4, kN = 6, kC = 64, kD = 41, kFH = 16, kFW = 44;
constexpr int kNX0 = 200, kNX1 = 200;
constexpr int kHW  = kFH * kFW;                    // 704
constexpr int kPix = kB * kN * kHW;                // 16896 pixels
constexpr int kPts = kPix * kD;                    // 692736 points
constexpr int kVox = kB * kNX0 * kNX1;             // 160000 voxels
constexpr int kPvElems = kPix * kC;                // 1081344
constexpr int kScanBlks = kVox / 256;              // 625 (exact)
constexpr int kPvtTiles = kPix / 64;               // 264

// ws carve (all chunk sizes multiples of 8)
constexpr size_t kOffPvT    = 0;
constexpr size_t kSzPvT     = (size_t)kPvElems * 4;
constexpr size_t kOffVox    = kOffPvT + kSzPvT;
constexpr size_t kSzVox     = (size_t)kPts * 4;
constexpr size_t kOffWgt    = kOffVox + kSzVox;
constexpr size_t kSzWgt     = (size_t)kPts * 4;
constexpr size_t kOffCnt    = kOffWgt + kSzWgt;
constexpr size_t kSzCnt     = (size_t)kVox * 4;
constexpr size_t kOffOffs   = kOffCnt + kSzCnt;
constexpr size_t kSzOffs    = 640256;              // 160001 u32, padded
constexpr size_t kOffBSum   = kOffOffs + kSzOffs;
constexpr size_t kSzBSum    = 2560;                // 625 u32, padded
constexpr size_t kOffSKW    = kOffBSum + kSzBSum;
constexpr size_t kSzSKW     = (size_t)kPts * 8;    // uint2 (pix, wgt-bits)
constexpr size_t kWsNeed    = kOffSKW + kSzSKW + 256;
}

__device__ __forceinline__ void inv3x3(const float m[9], float inv[9]) {
    float a = m[0], b = m[1], c = m[2];
    float d = m[3], e = m[4], f = m[5];
    float g = m[6], h = m[7], i = m[8];
    float A =  (e * i - f * h);
    float Bm = -(d * i - f * g);
    float Cm =  (d * h - e * g);
    float det = a * A + b * Bm + c * Cm;
    float r = 1.0f / det;
    inv[0] = A * r;
    inv[1] = -(b * i - c * h) * r;
    inv[2] =  (b * f - c * e) * r;
    inv[3] = Bm * r;
    inv[4] =  (a * i - c * g) * r;
    inv[5] = -(a * f - c * d) * r;
    inv[6] = Cm * r;
    inv[7] = -(a * h - b * g) * r;
    inv[8] =  (a * e - b * d) * r;
}

// ---- K0: LDS-transpose feat_pv [bn,C,hw] -> pvT [pix][C]; also zero counts.
//      grid = 625 blocks; first 264 also transpose one 64pix x 64c tile. ----
__global__ __launch_bounds__(256) void lss_pvt(const float* __restrict__ pv,
                                               float* __restrict__ pvT,
                                               unsigned* __restrict__ counts) {
    __shared__ float t[64][65];
    const int blk = blockIdx.x;
    const int tid = threadIdx.x;
    const int ci = blk * 256 + tid;
    if (ci < kVox) counts[ci] = 0u;

    if (blk < kPvtTiles) {
        const int pix0 = blk * 64;
        const int bn  = pix0 / kHW;
        const int hw0 = pix0 - bn * kHW;           // 64-aligned, tile within one bn
        const int lane = tid & 63;
        const int wv   = tid >> 6;
        const float* src = pv + (size_t)(bn * kC) * kHW + hw0;
#pragma unroll
        for (int cc = 0; cc < 16; ++cc) {
            const int c = wv * 16 + cc;
            t[c][lane] = src[(size_t)c * kHW + lane];   // coalesced 256B
        }
        __syncthreads();
        float* dst = pvT + (size_t)pix0 * kC;
#pragma unroll
        for (int jj = 0; jj < 16; ++jj) {
            const int j = wv * 16 + jj;
            dst[j * kC + lane] = t[lane][j];            // coalesced, pad-free banks
        }
    }
}

// ---- K1a: per-pixel softmax entirely in registers; one THREAD per pixel.
//      Writes all 41 weights to wgtArr in layout-major (d-major) order. ----
__global__ __launch_bounds__(256) void lss_sm(const float* __restrict__ feat_depth,
                                              float* __restrict__ wgtArr) {
    const int pix = blockIdx.x * 256 + threadIdx.x;    // 66 blocks exact
    const int bn = pix / kHW;
    const int hw = pix - bn * kHW;
    const float* p = feat_depth + (size_t)(bn * kD) * kHW + hw;
    float v[kD];
#pragma unroll
    for (int d = 0; d < kD; ++d) v[d] = p[(size_t)d * kHW];   // 41 coalesced loads
    float mx = v[0];
#pragma unroll
    for (int d = 1; d < kD; ++d) mx = fmaxf(mx, v[d]);
    float sm = 0.0f;
#pragma unroll
    for (int d = 0; d < kD; ++d) { v[d] = __expf(v[d] - mx); sm += v[d]; }
    const float inv = 1.0f / sm;
    float* o = wgtArr + (size_t)(bn * kD) * kHW + hw;
#pragma unroll
    for (int d = 0; d < kD; ++d) o[(size_t)d * kHW] = v[d] * inv;
}

// ---- K1b: per-POINT geometry (layout-major q); voxArr + counts histogram ----
__global__ __launch_bounds__(256) void lss_geo(
    const float* __restrict__ rots,
    const float* __restrict__ trans,
    const float* __restrict__ intrins,
    const float* __restrict__ post_rots,
    const float* __restrict__ post_trans,
    int* __restrict__ voxArr,
    unsigned* __restrict__ counts)
{
    const int q   = blockIdx.x * 256 + threadIdx.x;    // 2706 blocks exact
    const int bn  = q / (kD * kHW);
    const int rem = q - bn * (kD * kHW);
    const int d   = rem / kHW;
    const int hw  = rem - d * kHW;
    const int h   = hw / kFW;
    const int w   = hw - h * kFW;
    const int b   = bn / kN;

    const float* R  = rots       + bn * 9;
    const float* K  = intrins    + bn * 9;
    const float* PR = post_rots  + bn * 9;
    const float* PT = post_trans + bn * 3;
    const float* T  = trans      + bn * 3;

    float Km[9], PRm[9];
#pragma unroll
    for (int i = 0; i < 9; ++i) { Km[i] = K[i]; PRm[i] = PR[i]; }
    float invK[9], invPR[9];
    inv3x3(Km, invK);
    inv3x3(PRm, invPR);
    float M[9];
#pragma unroll
    for (int i = 0; i < 3; ++i)
#pragma unroll
        for (int j = 0; j < 3; ++j)
            M[i * 3 + j] = R[i * 3 + 0] * invK[0 * 3 + j]
                         + R[i * 3 + 1] * invK[1 * 3 + j]
                         + R[i * 3 + 2] * invK[2 * 3 + j];

    const float u  = (float)w * (703.0f / 43.0f);
    const float v  = (float)h * 17.0f;
    const float dv = 4.0f + (float)d;
    const float px = u - PT[0], py = v - PT[1], pz = dv - PT[2];
    const float ax = invPR[0] * px + invPR[1] * py + invPR[2] * pz;
    const float ay = invPR[3] * px + invPR[4] * py + invPR[5] * pz;
    const float az = invPR[6] * px + invPR[7] * py + invPR[8] * pz;
    const float qx = ax * az, qy = ay * az, qz = az;
    const float gx = M[0] * qx + M[1] * qy + M[2] * qz + T[0];
    const float gy = M[3] * qx + M[4] * qy + M[5] * qz + T[1];
    const float gz = M[6] * qx + M[7] * qy + M[8] * qz + T[2];
    const float fx = (gx + 50.0f) / 0.5f;
    const float fy = (gy + 50.0f) / 0.5f;
    const float fz = (gz + 10.0f) / 20.0f;
    const int gix = (int)fx;
    const int giy = (int)fy;
    const int giz = (int)fz;
    int flat = -1;
    if (gix >= 0 && gix < kNX0 && giy >= 0 && giy < kNX1 && giz == 0) {
        flat = (b * kNX0 + gix) * kNX1 + giy;
        atomicAdd(&counts[flat], 1u);
    }
    voxArr[q] = flat;
}

// ---- K2a: block-local exclusive scan (625 x 256, exact cover) ----
__global__ __launch_bounds__(256) void lss_scan_a(const unsigned* __restrict__ counts,
                                                  unsigned* __restrict__ offsets,
                                                  unsigned* __restrict__ blockSums) {
    const int i = blockIdx.x * 256 + threadIdx.x;
    const int lane = threadIdx.x & 63;
    const int wv = threadIdx.x >> 6;
    const unsigned c = counts[i];
    unsigned s = c;
#pragma unroll
    for (int o = 1; o < 64; o <<= 1) {
        unsigned v = __shfl_up(s, o);
        if (lane >= o) s += v;
    }
    __shared__ unsigned wsum[4];
    if (lane == 63) wsum[wv] = s;
    __syncthreads();
    unsigned base = 0;
#pragma unroll
    for (int k = 0; k < 3; ++k)
        if (k < wv) base += wsum[k];
    const unsigned incl = s + base;
    offsets[i] = incl - c;
    if (threadIdx.x == 255) blockSums[blockIdx.x] = incl;
}

// ---- K2b: scan 625 block sums (single block) ----
__global__ __launch_bounds__(1024) void lss_scan_b(unsigned* __restrict__ blockSums,
                                                   unsigned* __restrict__ offsets) {
    const int t = threadIdx.x;
    const int lane = t & 63;
    const int wv = t >> 6;
    const unsigned c = (t < kScanBlks) ? blockSums[t] : 0u;
    unsigned s = c;
#pragma unroll
    for (int o = 1; o < 64; o <<= 1) {
        unsigned v = __shfl_up(s, o);
        if (lane >= o) s += v;
    }
    __shared__ unsigned wsum[16];
    if (lane == 63) wsum[wv] = s;
    __syncthreads();
    unsigned base = 0;
#pragma unroll
    for (int k = 0; k < 15; ++k)
        if (k < wv) base += wsum[k];
    const unsigned incl = s + base;
    if (t < kScanBlks) blockSums[t] = incl - c;
    if (t == 1023) offsets[kVox] = incl;
}

// ---- K2c: add block base -> final exclusive offsets ----
__global__ __launch_bounds__(256) void lss_scan_c(const unsigned* __restrict__ blockSums,
                                                  unsigned* __restrict__ offsets) {
    const int i = blockIdx.x * 256 + threadIdx.x;
    offsets[i] += blockSums[blockIdx.x];
}

// ---- K3: scatter (pix, wgt) into CSR order; offsets doubles as cursor.
//      After this kernel, offsets[v] == end of segment v. ----
__global__ __launch_bounds__(256) void lss_order(const int* __restrict__ voxArr,
                                                 const float* __restrict__ wgtArr,
                                                 unsigned* __restrict__ offsets,
                                                 uint2* __restrict__ skw) {
    const int q = blockIdx.x * 256 + threadIdx.x;      // 2706 blocks exact
    const int f = voxArr[q];
    if (f >= 0) {
        const unsigned slot = atomicAdd(&offsets[f], 1u);
        const int bn  = q / (kD * kHW);
        const int rem = q - bn * (kD * kHW);
        const int hw  = rem % kHW;
        uint2 u;
        u.x = (unsigned)(bn * kHW + hw);               // pix
        u.y = __float_as_uint(wgtArr[q]);
        skw[slot] = u;
    }
}

// ---- K4: per-tile gather; LDS-staged CSR segment; register accumulate.
//      512 threads (8 waves) per block: wave cap = LDS cap -> full occupancy. ----
__global__ __launch_bounds__(512) void lss_gather(const float* __restrict__ pvT,
                                                  const unsigned* __restrict__ offsets,
                                                  const uint2* __restrict__ skw,
                                                  float* __restrict__ out) {
    constexpr int kChunk = 2048;                   // 16 KB staging buffer
    __shared__ float acc[50][65];                  // 13 KB
    __shared__ uint2 sbuf[kChunk];                 // 16 KB
    __shared__ unsigned rowOff[51];                // CSR bounds for the 50 rows
    const int tile = blockIdx.x;                   // b*800 + xi*4 + yt  (3200 total)
    const int yt = tile & 3;
    const int xi = (tile >> 2) % kNX0;
    const int b  = tile / (kNX0 * 4);
    const int yi0 = yt * 50;
    const int lane = threadIdx.x & 63;
    const int wave = threadIdx.x >> 6;             // 0..7
    const int flat0 = (b * kNX0 + xi) * kNX1 + yi0;

    for (int e = threadIdx.x; e < 50 * 65; e += 512)
        ((float*)acc)[e] = 0.0f;
    if (threadIdx.x < 51) {
        const int f = flat0 - 1 + (int)threadIdx.x;
        rowOff[threadIdx.x] = (f < 0) ? 0u : offsets[f];   // rowOff[j] = start of row j
    }
    __syncthreads();

    const unsigned seg0 = rowOff[0];
    const unsigned seg1 = rowOff[50];

    for (unsigned cb = seg0; cb < seg1; cb += (unsigned)kChunk) {
        const unsigned ce = min(cb + (unsigned)kChunk, seg1);
        const int n = (int)(ce - cb);
        for (int e = threadIdx.x; e < n; e += 512)
            sbuf[e] = skw[cb + e];
        __syncthreads();

        for (int j = wave; j < 50; j += 8) {
            unsigned s0 = max(rowOff[j], cb);
            unsigned e0 = min(rowOff[j + 1], ce);
            if (s0 >= e0) continue;
            float a0 = 0.0f, a1 = 0.0f, a2 = 0.0f, a3 = 0.0f;
            int p  = (int)(s0 - cb);
            int pe = (int)(e0 - cb);
            for (; p + 4 <= pe; p += 4) {
                const uint2 u0 = sbuf[p + 0];
                const uint2 u1 = sbuf[p + 1];
                const uint2 u2 = sbuf[p + 2];
                const uint2 u3 = sbuf[p + 3];
                a0 += __uint_as_float(u0.y) * pvT[u0.x * kC + lane];
                a1 += __uint_as_float(u1.y) * pvT[u1.x * kC + lane];
                a2 += __uint_as_float(u2.y) * pvT[u2.x * kC + lane];
                a3 += __uint_as_float(u3.y) * pvT[u3.x * kC + lane];
            }
            for (; p < pe; ++p) {
                const uint2 u = sbuf[p];
                a0 += __uint_as_float(u.y) * pvT[u.x * kC + lane];
            }
            acc[j][lane] += (a0 + a1) + (a2 + a3);
        }
        __syncthreads();                           // sbuf safe to overwrite next iter
    }
    __syncthreads();

    for (int e = threadIdx.x; e < kC * 50; e += 512) {
        const int c = e / 50, j = e % 50;
        out[((b * kC + c) * (kNX0 * kNX1)) + xi * kNX1 + yi0 + j] = acc[j][c];
    }
}

// ---- fallback: atomic path (used only if ws too small) ----
__global__ __launch_bounds__(256) void lss_scatter_fb(
    const float* __restrict__ feat_depth,
    const float* __restrict__ feat_pv,
    const float* __restrict__ rots,
    const float* __restrict__ trans,
    const float* __restrict__ intrins,
    const float* __restrict__ post_rots,
    const float* __restrict__ post_trans,
    float* __restrict__ out)
{
    const int lane = threadIdx.x & 63;
    const int wave = threadIdx.x >> 6;
    const int pix  = blockIdx.x * 4 + wave;
    const int w  = pix % kFW;
    const int h  = (pix / kFW) % kFH;
    const int bn = pix / kHW;
    const int b  = bn / kN;
    const float* R  = rots       + bn * 9;
    const float* K  = intrins    + bn * 9;
    const float* PR = post_rots  + bn * 9;
    const float* PT = post_trans + bn * 3;
    const float* T  = trans      + bn * 3;
    float Km[9], PRm[9];
#pragma unroll
    for (int i = 0; i < 9; ++i) { Km[i] = K[i]; PRm[i] = PR[i]; }
    float invK[9], invPR[9];
    inv3x3(Km, invK);
    inv3x3(PRm, invPR);
    float M[9];
#pragma unroll
    for (int i = 0; i < 3; ++i)
#pragma unroll
        for (int j = 0; j < 3; ++j)
            M[i * 3 + j] = R[i * 3 + 0] * invK[0 * 3 + j]
                         + R[i * 3 + 1] * invK[1 * 3 + j]
                         + R[i * 3 + 2] * invK[2 * 3 + j];
    const float pt0 = PT[0], pt1 = PT[1], pt2 = PT[2];
    const float t0 = T[0], t1 = T[1], t2 = T[2];
    const int pixBase = h * kFW + w;
    float fd = -INFINITY;
    if (lane < kD)
        fd = feat_depth[(bn * kD + lane) * kHW + pixBase];
    float mx = fd;
#pragma unroll
    for (int off = 32; off >= 1; off >>= 1)
        mx = fmaxf(mx, __shfl_xor(mx, off));
    float ex = (lane < kD) ? __expf(fd - mx) : 0.0f;
    float sm = ex;
#pragma unroll
    for (int off = 32; off >= 1; off >>= 1)
        sm += __shfl_xor(sm, off);
    const float wgt = ex / sm;
    int vox = -1;
    if (lane < kD) {
        const float u  = (float)w * (703.0f / 43.0f);
        const float v  = (float)h * 17.0f;
        const float dv = 4.0f + (float)lane;
        const float px = u - pt0, py = v - pt1, pz = dv - pt2;
        const float ax = invPR[0] * px + invPR[1] * py + invPR[2] * pz;
        const float ay = invPR[3] * px + invPR[4] * py + invPR[5] * pz;
        const float az = invPR[6] * px + invPR[7] * py + invPR[8] * pz;
        const float qx = ax * az, qy = ay * az, qz = az;
        const float gx = M[0] * qx + M[1] * qy + M[2] * qz + t0;
        const float gy = M[3] * qx + M[4] * qy + M[5] * qz + t1;
        const float gz = M[6] * qx + M[7] * qy + M[8] * qz + t2;
        const float fx = (gx + 50.0f) / 0.5f;
        const float fy = (gy + 50.0f) / 0.5f;
        const float fz = (gz + 10.0f) / 20.0f;
        const int gix = (int)fx;
        const int giy = (int)fy;
        const int giz = (int)fz;
        if (gix >= 0 && gix < kNX0 && giy >= 0 && giy < kNX1 && giz == 0)
            vox = gix * kNX1 + giy;
    }
    const float fc = feat_pv[(bn * kC + lane) * kHW + pixBase];
    const int outBase = (b * kC + lane) * (kNX0 * kNX1);
#pragma unroll 1
    for (int d = 0; d < kD; ++d) {
        const int   vd = __shfl(vox, d);
        const float wd = __shfl(wgt, d);
        if (vd >= 0)
            atomicAdd(&out[outBase + vd], wd * fc);
    }
}

extern "C" void kernel_launch(void* const* d_in, const int* in_sizes, int n_in,
                              void* d_out, int out_size, void* d_ws, size_t ws_size,
                              hipStream_t stream) {
    const float* feat_depth = (const float*)d_in[0];
    const float* feat_pv    = (const float*)d_in[1];
    const float* rots       = (const float*)d_in[2];
    const float* trans      = (const float*)d_in[3];
    const float* intrins    = (const float*)d_in[4];
    const float* post_rots  = (const float*)d_in[5];
    const float* post_trans = (const float*)d_in[6];
    float* out = (float*)d_out;

    if (ws_size < kWsNeed) {
        hipMemsetAsync(out, 0, (size_t)out_size * sizeof(float), stream);
        lss_scatter_fb<<<kPix / 4, 256, 0, stream>>>(
            feat_depth, feat_pv, rots, trans, intrins, post_rots, post_trans, out);
        return;
    }

    char* ws = (char*)d_ws;
    float*    pvT      = (float*)   (ws + kOffPvT);
    int*      voxArr   = (int*)     (ws + kOffVox);
    float*    wgtArr   = (float*)   (ws + kOffWgt);
    unsigned* counts   = (unsigned*)(ws + kOffCnt);
    unsigned* offsets  = (unsigned*)(ws + kOffOffs);
    unsigned* blockSums= (unsigned*)(ws + kOffBSum);
    uint2*    skw      = (uint2*)   (ws + kOffSKW);

    lss_pvt<<<kScanBlks, 256, 0, stream>>>(feat_pv, pvT, counts);
    lss_sm<<<kPix / 256, 256, 0, stream>>>(feat_depth, wgtArr);
    lss_geo<<<kPts / 256, 256, 0, stream>>>(
        rots, trans, intrins, post_rots, post_trans, voxArr, counts);
    lss_scan_a<<<kScanBlks, 256, 0, stream>>>(counts, offsets, blockSums);
    lss_scan_b<<<1, 1024, 0, stream>>>(blockSums, offsets);
    lss_scan_c<<<kScanBlks, 256, 0, stream>>>(blockSums, offsets);
    lss_order<<<kPts / 256, 256, 0, stream>>>(voxArr, wgtArr, offsets, skw);
    lss_gather<<<kB * kNX0 * 4, 512, 0, stream>>>(pvT, offsets, skw, out);
}